// Round 15
// baseline (49.481 us; speedup 1.0000x reference)
//
#include <hip/hip_runtime.h>
#include <hip/hip_bf16.h>

#define B_ 32
#define L_ 512
#define H_ 1024
#define E_ 8
#define R_ 16

typedef float f32x4 __attribute__((ext_vector_type(4)));
typedef __bf16 bf16x8 __attribute__((ext_vector_type(8)));
typedef __bf16 bf16x4 __attribute__((ext_vector_type(4)));

static __device__ __forceinline__ __bf16 f2b(float f) { return (__bf16)f; }

static __device__ __forceinline__ f32x4 MFMA(bf16x8 a, bf16x8 b, f32x4 c) {
  return __builtin_amdgcn_mfma_f32_16x16x32_bf16(a, b, c, 0, 0, 0);
}

// ---------------- prep: f32 weights -> bf16 in ws; + gates -----------------
__global__ __launch_bounds__(256) void moe_prep_kernel(
    const float* __restrict__ x, const float* __restrict__ rw,
    const float* __restrict__ ldown, const float* __restrict__ lup,
    __bf16* __restrict__ ldb, __bf16* __restrict__ lub,
    float* __restrict__ gws)
{
  const int bid = blockIdx.x;
  if (bid < 256) {                          // weight conversion: 2x131072 f32
    const int base = bid * 1024 + threadIdx.x * 4;
    const float* src; __bf16* dst; int off;
    if (base < 131072) { src = ldown; dst = ldb; off = base; }
    else               { src = lup;   dst = lub; off = base - 131072; }
    float4 v = *(const float4*)(src + off);
    bf16x4 bv = { f2b(v.x), f2b(v.y), f2b(v.z), f2b(v.w) };
    *(bf16x4*)(dst + off) = bv;
    return;
  }
  // gates for b = bid - 256
  const int b = bid - 256;
  const int t = threadIdx.x;
  const int e = t >> 5, s = t & 31;
  const float* cls = x + (size_t)b * L_ * H_;
  const float* w   = rw + (size_t)e * H_;
  float p = 0.f;
#pragma unroll
  for (int c = s; c < 256; c += 32) {
    float4 xv = *(const float4*)(cls + 4 * c);
    float4 wv = *(const float4*)(w + 4 * c);
    p += xv.x * wv.x + xv.y * wv.y + xv.z * wv.z + xv.w * wv.w;
  }
#pragma unroll
  for (int off = 16; off; off >>= 1) p += __shfl_down(p, off, 32);
  __shared__ float logits[E_];
  if (s == 0) logits[e] = p;
  __syncthreads();
  if (t == 0) {
    float m0 = -1e30f; int i0 = 0;
    for (int j = 0; j < E_; ++j) if (logits[j] > m0) { m0 = logits[j]; i0 = j; }
    float m1 = -1e30f; int i1 = 0;
    for (int j = 0; j < E_; ++j) if (j != i0 && logits[j] > m1) { m1 = logits[j]; i1 = j; }
    float eb = expf(m1 - m0), inv = 1.f / (1.f + eb);
    gws[b * 4 + 0] = inv;
    gws[b * 4 + 1] = eb * inv;
    ((int*)gws)[b * 4 + 2] = i0;
    ((int*)gws)[b * 4 + 3] = i1;
  }
}

// ---------------- gates-only fallback (no-ws path) -------------------------
__global__ __launch_bounds__(256) void moe_gates_kernel(
    const float* __restrict__ x, const float* __restrict__ rw,
    float* __restrict__ gws)
{
  const int b = blockIdx.x;
  const int t = threadIdx.x;
  const int e = t >> 5, s = t & 31;
  const float* cls = x + (size_t)b * L_ * H_;
  const float* w   = rw + (size_t)e * H_;
  float p = 0.f;
#pragma unroll
  for (int c = s; c < 256; c += 32) {
    float4 xv = *(const float4*)(cls + 4 * c);
    float4 wv = *(const float4*)(w + 4 * c);
    p += xv.x * wv.x + xv.y * wv.y + xv.z * wv.z + xv.w * wv.w;
  }
#pragma unroll
  for (int off = 16; off; off >>= 1) p += __shfl_down(p, off, 32);
  __shared__ float logits[E_];
  if (s == 0) logits[e] = p;
  __syncthreads();
  if (t == 0) {
    float m0 = -1e30f; int i0 = 0;
    for (int j = 0; j < E_; ++j) if (logits[j] > m0) { m0 = logits[j]; i0 = j; }
    float m1 = -1e30f; int i1 = 0;
    for (int j = 0; j < E_; ++j) if (j != i0 && logits[j] > m1) { m1 = logits[j]; i1 = j; }
    float eb = expf(m1 - m0), inv = 1.f / (1.f + eb);
    gws[b * 4 + 0] = inv;
    gws[b * 4 + 1] = eb * inv;
    ((int*)gws)[b * 4 + 2] = i0;
    ((int*)gws)[b * 4 + 3] = i1;
  }
}

// ---------------- main: R14 structure, LDS-atomic K-reduce (36.5 KB LDS ->
// 4 blocks/CU = 32 waves/CU). Phase B writes bf16 results in place over the
// residual quad in xs; streaming epilogue stores whole rows contiguously.
template<int BW>
__global__ __launch_bounds__(512, 8) void moe_main_kernel(
    const float* __restrict__ x,
    const __bf16* __restrict__ ldb, const __bf16* __restrict__ lub,
    const float* __restrict__ ldf, const float* __restrict__ luf,
    const float* __restrict__ gws, float* __restrict__ out)
{
  constexpr int XW = 1036;                  // 518 dwords/row, %32 == 6
  __shared__ __bf16 xs[16][XW];             // 33,152 B: x in, OUT (bf16) after B
  __shared__ float  dgf[2][16][16];         //  2,048 B: atomic K-reduce of D^T
  __shared__ __bf16 dg[16][40];             //  1,280 B: gated bf16 D

  const int t    = threadIdx.x;
  const int w    = t >> 6;                  // 0..7
  const int lane = t & 63;
  const int gq   = lane >> 4;
  const int r16  = lane & 15;

  const int bid  = blockIdx.x;
  const int tile = (bid & 7) * 128 + (bid >> 3);   // XCD swizzle (bijective)
  const int b    = tile >> 5;
  const int l0   = (tile & 31) * 16;

  const float g0 = gws[b * 4 + 0];
  const float g1 = gws[b * 4 + 1];
  const int   e0 = ((const int*)gws)[b * 4 + 2];
  const int   e1 = ((const int*)gws)[b * 4 + 3];

  const float* xb = x + ((size_t)b * L_ + l0) * H_;

  // ---- zero the atomic accumulator (covered by the stage barrier) ---------
  ((float*)dgf)[t] = 0.f;

  // ---- stage X tile as bf16 (wave w: rows 2w,2w+1; row-contiguous reads) --
  {
    const int row = 2 * w + (lane >> 5);
    const int c0  = (lane & 31) * 4;
    const float* xrr = xb + (size_t)row * H_;
#pragma unroll
    for (int i = 0; i < 8; ++i) {
      float4 v = *(const float4*)(xrr + c0 + i * 128);
      bf16x4 bv = { f2b(v.x), f2b(v.y), f2b(v.z), f2b(v.w) };
      *(bf16x4*)&xs[row][c0 + i * 128] = bv;
    }
  }
  __syncthreads();

  // ---- Phase A: wave w handles K slice [w*128, (w+1)*128) -----------------
  f32x4 acc0 = {0.f, 0.f, 0.f, 0.f};
  f32x4 acc1 = {0.f, 0.f, 0.f, 0.f};
#pragma unroll
  for (int s = 0; s < 4; ++s) {
    const int kl = w * 128 + s * 32 + 4 * gq;
    bf16x4 xlo = *(const bf16x4*)&xs[r16][kl];
    bf16x4 xhi = *(const bf16x4*)&xs[r16][kl + 16];
    bf16x8 xq = { xlo[0], xlo[1], xlo[2], xlo[3],
                  xhi[0], xhi[1], xhi[2], xhi[3] };
    bf16x8 wf0, wf1;
    if constexpr (BW) {
      const __bf16* w0p = ldb + ((size_t)e0 * R_ + r16) * H_;
      const __bf16* w1p = ldb + ((size_t)e1 * R_ + r16) * H_;
      bf16x4 a0 = *(const bf16x4*)(w0p + kl);
      bf16x4 a1 = *(const bf16x4*)(w0p + kl + 16);
      bf16x4 b0 = *(const bf16x4*)(w1p + kl);
      bf16x4 b1 = *(const bf16x4*)(w1p + kl + 16);
      wf0 = bf16x8{ a0[0],a0[1],a0[2],a0[3], a1[0],a1[1],a1[2],a1[3] };
      wf1 = bf16x8{ b0[0],b0[1],b0[2],b0[3], b1[0],b1[1],b1[2],b1[3] };
    } else {
      const float* w0p = ldf + ((size_t)e0 * R_ + r16) * H_;
      const float* w1p = ldf + ((size_t)e1 * R_ + r16) * H_;
      float4 alo = *(const float4*)(w0p + kl);
      float4 ahi = *(const float4*)(w0p + kl + 16);
      float4 blo = *(const float4*)(w1p + kl);
      float4 bhi = *(const float4*)(w1p + kl + 16);
      wf0 = bf16x8{ f2b(alo.x), f2b(alo.y), f2b(alo.z), f2b(alo.w),
                    f2b(ahi.x), f2b(ahi.y), f2b(ahi.z), f2b(ahi.w) };
      wf1 = bf16x8{ f2b(blo.x), f2b(blo.y), f2b(blo.z), f2b(blo.w),
                    f2b(bhi.x), f2b(bhi.y), f2b(bhi.z), f2b(bhi.w) };
    }
    acc0 = MFMA(wf0, xq, acc0);
    acc1 = MFMA(wf1, xq, acc1);
  }

  // ---- K-reduce via LDS atomics: D^T frag (col=l=r16, row=p=4gq+j) --------
#pragma unroll
  for (int j = 0; j < 4; ++j) {
    atomicAdd(&dgf[0][r16][4 * gq + j], acc0[j]);
    atomicAdd(&dgf[1][r16][4 * gq + j], acc1[j]);
  }
  __syncthreads();

  // ---- gate + pack dg[l][e*16+p] ------------------------------------------
  if (t < 128) {
    const int e = t >> 6, slot = t & 63;
    const int l  = slot & 15;
    const int p0 = (slot >> 4) * 4;
    const float g = e ? g1 : g0;
#pragma unroll
    for (int j = 0; j < 4; ++j)
      dg[l][e * 16 + p0 + j] = f2b(dgf[e][l][p0 + j] * g);
  }
  __syncthreads();

  // ---- Phase B: wave w covers h in [w*128, (w+1)*128); in-place results ---
  bf16x8 dfrag;
#pragma unroll
  for (int j = 0; j < 4; ++j) {
    dfrag[j]     = dg[r16][4 * gq + j];         // k=4gq+j      (e0)
    dfrag[4 + j] = dg[r16][16 + 4 * gq + j];    // k=16+4gq+j   (e1)
  }

#pragma unroll
  for (int nt = 0; nt < 8; ++nt) {
    const int h0 = w * 128 + nt * 16;
    const int ha = h0 + r16;
    bf16x8 uf;
    if constexpr (BW) {
      bf16x4 ulo = *(const bf16x4*)(lub + ((size_t)e0 * H_ + ha) * R_ + 4 * gq);
      bf16x4 uhi = *(const bf16x4*)(lub + ((size_t)e1 * H_ + ha) * R_ + 4 * gq);
      uf = bf16x8{ ulo[0],ulo[1],ulo[2],ulo[3], uhi[0],uhi[1],uhi[2],uhi[3] };
    } else {
      float4 ulo = *(const float4*)(luf + ((size_t)e0 * H_ + ha) * R_ + 4 * gq);
      float4 uhi = *(const float4*)(luf + ((size_t)e1 * H_ + ha) * R_ + 4 * gq);
      uf = bf16x8{ f2b(ulo.x), f2b(ulo.y), f2b(ulo.z), f2b(ulo.w),
                   f2b(uhi.x), f2b(uhi.y), f2b(uhi.z), f2b(uhi.w) };
    }
    bf16x4 rx = *(const bf16x4*)&xs[r16][h0 + 4 * gq];    // residual (bf16)
    f32x4 acc = { (float)rx[0], (float)rx[1], (float)rx[2], (float)rx[3] };
    acc = MFMA(uf, dfrag, acc);
    bf16x4 ov = { f2b(acc[0]), f2b(acc[1]), f2b(acc[2]), f2b(acc[3]) };
    *(bf16x4*)&xs[r16][h0 + 4 * gq] = ov;     // in-place: same lane, same quad
  }
  __syncthreads();

  // ---- epilogue: stream whole rows out (512B contiguous per instruction) --
  {
    const int row = 2 * w + (lane >> 5);
    const int l32 = lane & 31;
    float* outrow = out + ((size_t)b * L_ + l0 + row) * H_;
#pragma unroll
    for (int it = 0; it < 8; ++it) {
      const int col = it * 128 + l32 * 4;
      bf16x4 v = *(const bf16x4*)&xs[row][col];
      float4 o = { (float)v[0], (float)v[1], (float)v[2], (float)v[3] };
      *(float4*)(outrow + col) = o;
    }
  }
}

extern "C" void kernel_launch(void* const* d_in, const int* in_sizes, int n_in,
                              void* d_out, int out_size, void* d_ws, size_t ws_size,
                              hipStream_t stream) {
  const float* x  = (const float*)d_in[0];
  const float* rw = (const float*)d_in[1];
  const float* ld = (const float*)d_in[2];
  const float* lu = (const float*)d_in[3];
  float* outp = (float*)d_out;

  float*  gws = (float*)d_ws;                         // 512 B
  __bf16* ldb = (__bf16*)((char*)d_ws + 1024);        // 256 KB
  __bf16* lub = ldb + 131072;                         // 256 KB

  if (ws_size >= 1024 + 2 * 131072 * sizeof(__bf16)) {
    hipLaunchKernelGGL(moe_prep_kernel, dim3(256 + B_), dim3(256), 0, stream,
                       x, rw, ld, lu, ldb, lub, gws);
    hipLaunchKernelGGL(moe_main_kernel<1>, dim3(1024), dim3(512), 0, stream,
                       x, ldb, lub, nullptr, nullptr, gws, outp);
  } else {
    hipLaunchKernelGGL(moe_gates_kernel, dim3(B_), dim3(256), 0, stream,
                       x, rw, gws);
    hipLaunchKernelGGL(moe_main_kernel<0>, dim3(1024), dim3(512), 0, stream,
                       x, nullptr, nullptr, ld, lu, gws, outp);
  }
}

// Round 16
// 49.331 us; speedup vs baseline: 1.0030x; 1.0030x over previous
//
#include <hip/hip_runtime.h>
#include <hip/hip_bf16.h>

#define B_ 32
#define L_ 512
#define H_ 1024
#define E_ 8
#define R_ 16

typedef float f32x4 __attribute__((ext_vector_type(4)));
typedef __bf16 bf16x8 __attribute__((ext_vector_type(8)));
typedef __bf16 bf16x4 __attribute__((ext_vector_type(4)));

static __device__ __forceinline__ __bf16 f2b(float f) { return (__bf16)f; }

static __device__ __forceinline__ f32x4 MFMA(bf16x8 a, bf16x8 b, f32x4 c) {
  return __builtin_amdgcn_mfma_f32_16x16x32_bf16(a, b, c, 0, 0, 0);
}

// ---------------- prep: f32 weights -> bf16 in ws; + gates -----------------
__global__ __launch_bounds__(256) void moe_prep_kernel(
    const float* __restrict__ x, const float* __restrict__ rw,
    const float* __restrict__ ldown, const float* __restrict__ lup,
    __bf16* __restrict__ ldb, __bf16* __restrict__ lub,
    float* __restrict__ gws)
{
  const int bid = blockIdx.x;
  if (bid < 256) {                          // weight conversion: 2x131072 f32
    const int base = bid * 1024 + threadIdx.x * 4;
    const float* src; __bf16* dst; int off;
    if (base < 131072) { src = ldown; dst = ldb; off = base; }
    else               { src = lup;   dst = lub; off = base - 131072; }
    float4 v = *(const float4*)(src + off);
    bf16x4 bv = { f2b(v.x), f2b(v.y), f2b(v.z), f2b(v.w) };
    *(bf16x4*)(dst + off) = bv;
    return;
  }
  // gates for b = bid - 256
  const int b = bid - 256;
  const int t = threadIdx.x;
  const int e = t >> 5, s = t & 31;
  const float* cls = x + (size_t)b * L_ * H_;
  const float* w   = rw + (size_t)e * H_;
  float p = 0.f;
#pragma unroll
  for (int c = s; c < 256; c += 32) {
    float4 xv = *(const float4*)(cls + 4 * c);
    float4 wv = *(const float4*)(w + 4 * c);
    p += xv.x * wv.x + xv.y * wv.y + xv.z * wv.z + xv.w * wv.w;
  }
#pragma unroll
  for (int off = 16; off; off >>= 1) p += __shfl_down(p, off, 32);
  __shared__ float logits[E_];
  if (s == 0) logits[e] = p;
  __syncthreads();
  if (t == 0) {
    float m0 = -1e30f; int i0 = 0;
    for (int j = 0; j < E_; ++j) if (logits[j] > m0) { m0 = logits[j]; i0 = j; }
    float m1 = -1e30f; int i1 = 0;
    for (int j = 0; j < E_; ++j) if (j != i0 && logits[j] > m1) { m1 = logits[j]; i1 = j; }
    float eb = expf(m1 - m0), inv = 1.f / (1.f + eb);
    gws[b * 4 + 0] = inv;
    gws[b * 4 + 1] = eb * inv;
    ((int*)gws)[b * 4 + 2] = i0;
    ((int*)gws)[b * 4 + 3] = i1;
  }
}

// ---------------- gates-only fallback (no-ws path) -------------------------
__global__ __launch_bounds__(256) void moe_gates_kernel(
    const float* __restrict__ x, const float* __restrict__ rw,
    float* __restrict__ gws)
{
  const int b = blockIdx.x;
  const int t = threadIdx.x;
  const int e = t >> 5, s = t & 31;
  const float* cls = x + (size_t)b * L_ * H_;
  const float* w   = rw + (size_t)e * H_;
  float p = 0.f;
#pragma unroll
  for (int c = s; c < 256; c += 32) {
    float4 xv = *(const float4*)(cls + 4 * c);
    float4 wv = *(const float4*)(w + 4 * c);
    p += xv.x * wv.x + xv.y * wv.y + xv.z * wv.z + xv.w * wv.w;
  }
#pragma unroll
  for (int off = 16; off; off >>= 1) p += __shfl_down(p, off, 32);
  __shared__ float logits[E_];
  if (s == 0) logits[e] = p;
  __syncthreads();
  if (t == 0) {
    float m0 = -1e30f; int i0 = 0;
    for (int j = 0; j < E_; ++j) if (logits[j] > m0) { m0 = logits[j]; i0 = j; }
    float m1 = -1e30f; int i1 = 0;
    for (int j = 0; j < E_; ++j) if (j != i0 && logits[j] > m1) { m1 = logits[j]; i1 = j; }
    float eb = expf(m1 - m0), inv = 1.f / (1.f + eb);
    gws[b * 4 + 0] = inv;
    gws[b * 4 + 1] = eb * inv;
    ((int*)gws)[b * 4 + 2] = i0;
    ((int*)gws)[b * 4 + 3] = i1;
  }
}

// ---------------- main: 2 tiles/block, read/write-mixed middle step --------
// Per block (512 thr, 8 waves): tiles t0,t1 (same b). Schedule:
//   stage(buf0) | A(t0) | pack | B(t0) | [epilogue(t0) + stage(buf1)] |
//   A(t1) | pack | B(t1) | epilogue(t1)
// The merged middle step streams HBM writes and reads concurrently
// (probe-like mixed traffic) instead of the chip-wide phase-locked
// read-epoch/write-epoch pattern of R10-R15.
template<int BW>
__global__ __launch_bounds__(512, 4) void moe_main_kernel(
    const float* __restrict__ x,
    const __bf16* __restrict__ ldb, const __bf16* __restrict__ lub,
    const float* __restrict__ ldf, const float* __restrict__ luf,
    const float* __restrict__ gws, float* __restrict__ out)
{
  constexpr int XW = 1036;                  // 518 dwords/row, %32 == 6
  __shared__ __bf16 xs0[16][XW];            // 33,152 B  tile0 (x in, out after B)
  __shared__ __bf16 xs1[16][XW];            // 33,152 B  tile1
  __shared__ float  dgf[2][16][16];         //  2,048 B  atomic K-reduce
  __shared__ __bf16 dg[16][40];             //  1,280 B  gated bf16 D

  const int t    = threadIdx.x;
  const int w    = t >> 6;                  // 0..7
  const int lane = t & 63;
  const int gq   = lane >> 4;
  const int r16  = lane & 15;

  const int bid = blockIdx.x;               // 512 blocks
  const int swz = (bid & 7) * 64 + (bid >> 3);    // XCD swizzle (bijective)
  const int t0  = swz * 2;                  // tiles t0, t0+1 (same b)
  const int b   = t0 >> 5;
  const int l00 = (t0 & 31) * 16;
  const int l01 = l00 + 16;

  const float g0 = gws[b * 4 + 0];
  const float g1 = gws[b * 4 + 1];
  const int   e0 = ((const int*)gws)[b * 4 + 2];
  const int   e1 = ((const int*)gws)[b * 4 + 3];

  const int row = 2 * w + (lane >> 5);      // staging/epilogue row for this lane
  const int c0  = (lane & 31) * 4;

  // ---- zero atomic accumulator (covered by stage barrier) -----------------
  ((float*)dgf)[t] = 0.f;

  // ---- step 0: stage tile0 ------------------------------------------------
  {
    const float* xrr = x + ((size_t)b * L_ + l00 + row) * H_;
#pragma unroll
    for (int i = 0; i < 8; ++i) {
      float4 v = *(const float4*)(xrr + c0 + i * 128);
      bf16x4 bv = { f2b(v.x), f2b(v.y), f2b(v.z), f2b(v.w) };
      *(bf16x4*)&xs0[row][c0 + i * 128] = bv;
    }
  }
  __syncthreads();

  // ======================= tile0: phase A ==================================
#pragma unroll 1
  for (int tile = 0; tile < 2; ++tile) {
    __bf16 (*xs)[XW] = tile ? xs1 : xs0;

    // ---- phase A: wave w covers K slice [w*128,(w+1)*128) -----------------
    f32x4 acc0 = {0.f, 0.f, 0.f, 0.f};
    f32x4 acc1 = {0.f, 0.f, 0.f, 0.f};
#pragma unroll
    for (int s = 0; s < 4; ++s) {
      const int kl = w * 128 + s * 32 + 4 * gq;
      bf16x4 xlo = *(const bf16x4*)&xs[r16][kl];
      bf16x4 xhi = *(const bf16x4*)&xs[r16][kl + 16];
      bf16x8 xq = { xlo[0], xlo[1], xlo[2], xlo[3],
                    xhi[0], xhi[1], xhi[2], xhi[3] };
      bf16x8 wf0, wf1;
      if constexpr (BW) {
        const __bf16* w0p = ldb + ((size_t)e0 * R_ + r16) * H_;
        const __bf16* w1p = ldb + ((size_t)e1 * R_ + r16) * H_;
        bf16x4 a0 = *(const bf16x4*)(w0p + kl);
        bf16x4 a1 = *(const bf16x4*)(w0p + kl + 16);
        bf16x4 b0 = *(const bf16x4*)(w1p + kl);
        bf16x4 b1 = *(const bf16x4*)(w1p + kl + 16);
        wf0 = bf16x8{ a0[0],a0[1],a0[2],a0[3], a1[0],a1[1],a1[2],a1[3] };
        wf1 = bf16x8{ b0[0],b0[1],b0[2],b0[3], b1[0],b1[1],b1[2],b1[3] };
      } else {
        const float* w0p = ldf + ((size_t)e0 * R_ + r16) * H_;
        const float* w1p = ldf + ((size_t)e1 * R_ + r16) * H_;
        float4 alo = *(const float4*)(w0p + kl);
        float4 ahi = *(const float4*)(w0p + kl + 16);
        float4 blo = *(const float4*)(w1p + kl);
        float4 bhi = *(const float4*)(w1p + kl + 16);
        wf0 = bf16x8{ f2b(alo.x), f2b(alo.y), f2b(alo.z), f2b(alo.w),
                      f2b(ahi.x), f2b(ahi.y), f2b(ahi.z), f2b(ahi.w) };
        wf1 = bf16x8{ f2b(blo.x), f2b(blo.y), f2b(blo.z), f2b(blo.w),
                      f2b(bhi.x), f2b(bhi.y), f2b(bhi.z), f2b(bhi.w) };
      }
      acc0 = MFMA(wf0, xq, acc0);
      acc1 = MFMA(wf1, xq, acc1);
    }
#pragma unroll
    for (int j = 0; j < 4; ++j) {
      atomicAdd(&dgf[0][r16][4 * gq + j], acc0[j]);
      atomicAdd(&dgf[1][r16][4 * gq + j], acc1[j]);
    }
    __syncthreads();

    // ---- pack dg + re-zero dgf -------------------------------------------
    if (t < 128) {
      const int e = t >> 6, slot = t & 63;
      const int l  = slot & 15;
      const int p0 = (slot >> 4) * 4;
      const float g = e ? g1 : g0;
#pragma unroll
      for (int j = 0; j < 4; ++j) {
        dg[l][e * 16 + p0 + j] = f2b(dgf[e][l][p0 + j] * g);
        dgf[e][l][p0 + j] = 0.f;
      }
    }
    __syncthreads();

    // ---- phase B: wave w covers h in [w*128,(w+1)*128); in-place ----------
    bf16x8 dfrag;
#pragma unroll
    for (int j = 0; j < 4; ++j) {
      dfrag[j]     = dg[r16][4 * gq + j];       // k=4gq+j      (e0)
      dfrag[4 + j] = dg[r16][16 + 4 * gq + j];  // k=16+4gq+j   (e1)
    }
#pragma unroll
    for (int nt = 0; nt < 8; ++nt) {
      const int h0 = w * 128 + nt * 16;
      const int ha = h0 + r16;
      bf16x8 uf;
      if constexpr (BW) {
        bf16x4 ulo = *(const bf16x4*)(lub + ((size_t)e0 * H_ + ha) * R_ + 4 * gq);
        bf16x4 uhi = *(const bf16x4*)(lub + ((size_t)e1 * H_ + ha) * R_ + 4 * gq);
        uf = bf16x8{ ulo[0],ulo[1],ulo[2],ulo[3], uhi[0],uhi[1],uhi[2],uhi[3] };
      } else {
        float4 ulo = *(const float4*)(luf + ((size_t)e0 * H_ + ha) * R_ + 4 * gq);
        float4 uhi = *(const float4*)(luf + ((size_t)e1 * H_ + ha) * R_ + 4 * gq);
        uf = bf16x8{ f2b(ulo.x), f2b(ulo.y), f2b(ulo.z), f2b(ulo.w),
                     f2b(uhi.x), f2b(uhi.y), f2b(uhi.z), f2b(uhi.w) };
      }
      bf16x4 rx = *(const bf16x4*)&xs[r16][h0 + 4 * gq];
      f32x4 acc = { (float)rx[0], (float)rx[1], (float)rx[2], (float)rx[3] };
      acc = MFMA(uf, dfrag, acc);
      bf16x4 ov = { f2b(acc[0]), f2b(acc[1]), f2b(acc[2]), f2b(acc[3]) };
      *(bf16x4*)&xs[r16][h0 + 4 * gq] = ov;
    }
    __syncthreads();

    if (tile == 0) {
      // ---- merged step: epilogue(tile0) stores + stage(tile1) loads -------
      const float* xr1 = x + ((size_t)b * L_ + l01 + row) * H_;
      float4 v0 = *(const float4*)(xr1 + c0 + 0 * 128);
      float4 v1 = *(const float4*)(xr1 + c0 + 1 * 128);
      float4 v2 = *(const float4*)(xr1 + c0 + 2 * 128);
      float4 v3 = *(const float4*)(xr1 + c0 + 3 * 128);
      float4 v4 = *(const float4*)(xr1 + c0 + 4 * 128);
      float4 v5 = *(const float4*)(xr1 + c0 + 5 * 128);
      float4 v6 = *(const float4*)(xr1 + c0 + 6 * 128);
      float4 v7 = *(const float4*)(xr1 + c0 + 7 * 128);

      float* outrow = out + ((size_t)b * L_ + l00 + row) * H_;
#pragma unroll
      for (int it = 0; it < 8; ++it) {
        const int col = it * 128 + (lane & 31) * 4;
        bf16x4 vv = *(const bf16x4*)&xs0[row][col];
        float4 o = { (float)vv[0], (float)vv[1], (float)vv[2], (float)vv[3] };
        *(float4*)(outrow + col) = o;
      }

      bf16x4 s0 = { f2b(v0.x), f2b(v0.y), f2b(v0.z), f2b(v0.w) };
      bf16x4 s1 = { f2b(v1.x), f2b(v1.y), f2b(v1.z), f2b(v1.w) };
      bf16x4 s2 = { f2b(v2.x), f2b(v2.y), f2b(v2.z), f2b(v2.w) };
      bf16x4 s3 = { f2b(v3.x), f2b(v3.y), f2b(v3.z), f2b(v3.w) };
      bf16x4 s4 = { f2b(v4.x), f2b(v4.y), f2b(v4.z), f2b(v4.w) };
      bf16x4 s5 = { f2b(v5.x), f2b(v5.y), f2b(v5.z), f2b(v5.w) };
      bf16x4 s6 = { f2b(v6.x), f2b(v6.y), f2b(v6.z), f2b(v6.w) };
      bf16x4 s7 = { f2b(v7.x), f2b(v7.y), f2b(v7.z), f2b(v7.w) };
      *(bf16x4*)&xs1[row][c0 + 0 * 128] = s0;
      *(bf16x4*)&xs1[row][c0 + 1 * 128] = s1;
      *(bf16x4*)&xs1[row][c0 + 2 * 128] = s2;
      *(bf16x4*)&xs1[row][c0 + 3 * 128] = s3;
      *(bf16x4*)&xs1[row][c0 + 4 * 128] = s4;
      *(bf16x4*)&xs1[row][c0 + 5 * 128] = s5;
      *(bf16x4*)&xs1[row][c0 + 6 * 128] = s6;
      *(bf16x4*)&xs1[row][c0 + 7 * 128] = s7;
      __syncthreads();
    } else {
      // ---- final epilogue (tile1) ----------------------------------------
      float* outrow = out + ((size_t)b * L_ + l01 + row) * H_;
#pragma unroll
      for (int it = 0; it < 8; ++it) {
        const int col = it * 128 + (lane & 31) * 4;
        bf16x4 vv = *(const bf16x4*)&xs1[row][col];
        float4 o = { (float)vv[0], (float)vv[1], (float)vv[2], (float)vv[3] };
        *(float4*)(outrow + col) = o;
      }
    }
  }
}

extern "C" void kernel_launch(void* const* d_in, const int* in_sizes, int n_in,
                              void* d_out, int out_size, void* d_ws, size_t ws_size,
                              hipStream_t stream) {
  const float* x  = (const float*)d_in[0];
  const float* rw = (const float*)d_in[1];
  const float* ld = (const float*)d_in[2];
  const float* lu = (const float*)d_in[3];
  float* outp = (float*)d_out;

  float*  gws = (float*)d_ws;                         // 512 B
  __bf16* ldb = (__bf16*)((char*)d_ws + 1024);        // 256 KB
  __bf16* lub = ldb + 131072;                         // 256 KB

  if (ws_size >= 1024 + 2 * 131072 * sizeof(__bf16)) {
    hipLaunchKernelGGL(moe_prep_kernel, dim3(256 + B_), dim3(256), 0, stream,
                       x, rw, ld, lu, ldb, lub, gws);
    hipLaunchKernelGGL(moe_main_kernel<1>, dim3(512), dim3(512), 0, stream,
                       x, ldb, lub, nullptr, nullptr, gws, outp);
  } else {
    hipLaunchKernelGGL(moe_gates_kernel, dim3(B_), dim3(256), 0, stream,
                       x, rw, gws);
    hipLaunchKernelGGL(moe_main_kernel<0>, dim3(512), dim3(512), 0, stream,
                       x, nullptr, nullptr, ld, lu, gws, outp);
  }
}